// Round 1
// 19364.595 us; speedup vs baseline: 1.0600x; 1.0600x over previous
//
#include <hip/hip_runtime.h>
#include <cstdint>

#define HID 200
#define HALF 100
#define N_EDUS 32768
#define N_STEPS (2*N_EDUS - 1)   // 65535
#define KMAX 32766               // chain computes M_1..M_32766 (M_0 = enc[0])
#define PSTRIDE 500

typedef __fp16 h2v __attribute__((ext_vector_type(2)));
typedef _Float16 f16x8 __attribute__((ext_vector_type(8)));
typedef float f32x4 __attribute__((ext_vector_type(4)));

// ---------------- generic tiled GEMM: C[m][n] = bias[n] + sum_k A[m][k]*B[n][k] ----------------
__global__ __launch_bounds__(256) void gemm_bt(const float* __restrict__ A, int lda,
    const float* __restrict__ B, int ldb, const float* __restrict__ bias,
    float* __restrict__ C, int ldc, int M, int N, int K)
{
    __shared__ float As[32][68];
    __shared__ float Bs[32][68];
    const int tid = threadIdx.x;
    const int tx = tid & 15, ty = tid >> 4;
    const int m0 = blockIdx.x * 64, n0 = blockIdx.y * 64;
    float acc[4][4] = {};
    for (int kc = 0; kc < K; kc += 32) {
        const int kk = tid & 31, r0 = tid >> 5;
        #pragma unroll
        for (int p = 0; p < 8; ++p) {
            const int mm = r0 + p * 8;
            const int m = m0 + mm, n = n0 + mm, kg = kc + kk;
            As[kk][mm] = (m < M && kg < K) ? A[(size_t)m * lda + kg] : 0.f;
            Bs[kk][mm] = (n < N && kg < K) ? B[(size_t)n * ldb + kg] : 0.f;
        }
        __syncthreads();
        #pragma unroll
        for (int kk2 = 0; kk2 < 32; ++kk2) {
            const float4 a = *(const float4*)&As[kk2][tx * 4];
            const float4 b = *(const float4*)&Bs[kk2][ty * 4];
            const float av[4] = {a.x, a.y, a.z, a.w};
            const float bv[4] = {b.x, b.y, b.z, b.w};
            #pragma unroll
            for (int r = 0; r < 4; ++r)
                #pragma unroll
                for (int c = 0; c < 4; ++c)
                    acc[r][c] += av[r] * bv[c];
        }
        __syncthreads();
    }
    #pragma unroll
    for (int r = 0; r < 4; ++r) {
        const int m = m0 + tx * 4 + r;
        if (m >= M) continue;
        #pragma unroll
        for (int c = 0; c < 4; ++c) {
            const int n = n0 + ty * 4 + c;
            if (n < N) C[(size_t)m * ldc + n] = acc[r][c] + (bias ? bias[n] : 0.f);
        }
    }
}

// ---------------- prep (loss weight stacking + missing projections) ----------------
__global__ void prep_kernel(const float* __restrict__ W_act, const float* __restrict__ W_lab,
    const float* __restrict__ W_dir, const float* __restrict__ miss,
    float* __restrict__ WAB, float* __restrict__ WBC,
    float* __restrict__ msAB, float* __restrict__ msBC, float* __restrict__ out)
{
    const int tid = threadIdx.x;
    if (tid == 0) out[0] = 0.f;
    for (int i = tid; i < 48 * 200; i += 256) {
        const int r = i / 200, c = i % 200;
        const int rr = r % 24;
        const float* src = (rr < 2) ? (W_act + rr * 600)
                         : (rr < 21) ? (W_lab + (rr - 2) * 600)
                                     : (W_dir + (rr - 21) * 600);
        WAB[i] = src[c + (r < 24 ? 0 : 200)];
        WBC[i] = src[c + (r < 24 ? 200 : 400)];
    }
    __syncthreads();
    if (tid < 48) {
        float sA = 0.f, sB = 0.f;
        for (int c = 0; c < 200; ++c) {
            sA += WAB[tid * 200 + c] * miss[c];
            sB += WBC[tid * 200 + c] * miss[c];
        }
        msAB[tid] = sA;
        msBC[tid] = sB;
    }
}

// ---------------- pack W_tree[:,0:100] into MFMA A-fragment layout ----------------
// Frag id f = ((g*7 + w)*4 + kc); lane l holds A[row = w*16 + (l&15)][k = kc*32 + (l>>4)*8 + j],
// j=0..7 as f16 pairs (even k low half). Zero-padded rows>=100 / k>=100.
__global__ __launch_bounds__(256) void pack_wa(const float* __restrict__ W_tree,
                                               uint4* __restrict__ WA)
{
    const int i = blockIdx.x * 256 + threadIdx.x;   // 5*7*4*64 = 8960
    if (i >= 8960) return;
    const int lane = i & 63, f = i >> 6;
    const int kc = f & 3, gw = f >> 2;
    const int w = gw % 7, g = gw / 7;
    const int row = w * 16 + (lane & 15);
    const int kb = kc * 32 + (lane >> 4) * 8;
    unsigned int dws[4];
    #pragma unroll
    for (int dw = 0; dw < 4; ++dw) {
        const int k0 = kb + dw * 2;
        float w0 = 0.f, w1 = 0.f;
        if (row < 100) {
            if (k0 < 100)     w0 = W_tree[(size_t)(g * 100 + row) * 200 + k0];
            if (k0 + 1 < 100) w1 = W_tree[(size_t)(g * 100 + row) * 200 + k0 + 1];
        }
        h2v h = __builtin_amdgcn_cvt_pkrtz(w0, w1);
        __builtin_memcpy(&dws[dw], &h, 4);
    }
    uint4 v; v.x = dws[0]; v.y = dws[1]; v.z = dws[2]; v.w = dws[3];
    WA[i] = v;
}

// ---------------- sequential treelstm chain (MFMA) ----------------
__device__ __forceinline__ float sigf(float x) {
    return __builtin_amdgcn_rcpf(1.f + __expf(-x));
}
__device__ __forceinline__ float tanhf_(float x) {
    return 1.f - 2.f * __builtin_amdgcn_rcpf(1.f + __expf(2.f * x));
}

// raw barrier: drain LDS only, leave global prefetch loads (vmcnt) in flight
#define BAR() asm volatile("s_waitcnt lgkmcnt(0)\n\ts_barrier" ::: "memory")

// select reg rsel (loop-invariant masks hoisted by compiler -> 3 cndmask)
#define SELR(v) ((rsel & 2) ? ((rsel & 1) ? (v)[3] : (v)[2]) : ((rsel & 1) ? (v)[1] : (v)[0]))

// One chain step. U = ring slot (0..3) & LDS parity (U&1), compile-time.
#define BODY(U, DOLOAD) \
{ \
    const uint4* hb = (const uint4*)(&hbuf[(U) & 1][0]); \
    f16x8 bb[4]; \
    { \
        uint4 t0 = hb[kgrp];      uint4 t1 = hb[4 + kgrp]; \
        uint4 t2 = hb[8 + kgrp];  uint4 t3 = hb[12 + kgrp]; \
        __builtin_memcpy(&bb[0], &t0, 16); __builtin_memcpy(&bb[1], &t1, 16); \
        __builtin_memcpy(&bb[2], &t2, 16); __builtin_memcpy(&bb[3], &t3, 16); \
    } \
    f32x4 acc[5]; \
    _Pragma("unroll") \
    for (int g = 0; g < 5; ++g) acc[g] = (f32x4){0.f, 0.f, 0.f, 0.f}; \
    _Pragma("unroll") \
    for (int kc = 0; kc < 4; ++kc) { \
        _Pragma("unroll") \
        for (int g = 0; g < 5; ++g) \
            acc[g] = __builtin_amdgcn_mfma_f32_16x16x32_f16(A[g][kc], bb[kc], acc[g], 0, 0, 0); \
    } \
    const float gi  = SELR(acc[0]) + pr[U][0]; \
    const float gf1 = SELR(acc[1]) + pr[U][1]; \
    const float gf2 = SELR(acc[2]) + pr[U][2]; \
    const float go  = SELR(acc[3]) + pr[U][3]; \
    const float gu  = SELR(acc[4]) + pr[U][4]; \
    const float c2v = pr[U][5]; \
    if (DOLOAD) { \
        pr[U][0] = pP[0];   pr[U][1] = pP[100]; pr[U][2] = pP[200]; \
        pr[U][3] = pP[300]; pr[U][4] = pP[400]; pP += PSTRIDE; \
        pr[U][5] = *pE; pE += HID; \
    } \
    const float cnew = sigf(gi) * tanhf_(gu) + sigf(gf1) * c_sel + sigf(gf2) * c2v; \
    const float hnew = sigf(go) * tanhf_(cnew); \
    c_sel = cnew; \
    if (act) { \
        pM[0] = hnew; pM[100] = cnew; \
        hbuf[((U) & 1) ^ 1][row_c] = (_Float16)hnew; \
    } \
    pM += HID; \
    BAR(); \
}

__attribute__((amdgpu_flat_work_group_size(448, 448), amdgpu_waves_per_eu(2, 2)))
__global__ void chain_kernel(const float* __restrict__ enc,
    const uint4* __restrict__ WA, const float* __restrict__ P, float* __restrict__ M)
{
    const int T = threadIdx.x;
    const int wave = T >> 6, lane = T & 63;
    const int col = lane & 15, kgrp = lane >> 4;
    const int rsel = col & 3;
    const int row_c = wave * 16 + kgrp * 4 + rsel;   // 0..111
    const bool act = (col < 4) && (row_c < 100);
    __shared__ __align__(16) _Float16 hbuf[2][128];

    if (T < 200) M[T] = enc[T];   // M_0 = enc[0]
    if (T < 128) {
        hbuf[0][T] = (T < 100) ? (_Float16)enc[T] : (_Float16)0.f;  // h of M_0, zero pad
        hbuf[1][T] = (_Float16)0.f;                                  // pad rows stay 0 forever
    }

    // W fragments in registers/AGPRs for the whole chain: 20 frags x 16B
    f16x8 A[5][4];
    #pragma unroll
    for (int g = 0; g < 5; ++g)
        #pragma unroll
        for (int kc = 0; kc < 4; ++kc) {
            uint4 t = WA[((g * 7 + wave) * 4 + kc) * 64 + lane];
            __builtin_memcpy(&A[g][kc], &t, 16);
        }

    float c_sel = enc[100 + row_c];   // c of M_0 for this lane's row

    // 4-deep prefetch ring: slot u holds P row (1+u) gate biases + enc c2 row (1+u)
    float pr[4][6];
    #pragma unroll
    for (int u = 0; u < 4; ++u) {
        #pragma unroll
        for (int g = 0; g < 5; ++g)
            pr[u][g] = P[(size_t)(1 + u) * PSTRIDE + g * 100 + row_c];
        pr[u][5] = enc[(size_t)(1 + u) * HID + 100 + row_c];
    }
    const float* pP = P + (size_t)5 * PSTRIDE + row_c;      // next prefetch = step 5
    const float* pE = enc + (size_t)5 * HID + 100 + row_c;
    float* pM = M + HID + row_c;                            // step-1 store slot
    BAR();

    // main loop: 8190 iterations x 4 steps = steps 1..32760
    for (int base = 1; base <= KMAX - 9; base += 4) {
        BODY(0, true);
        BODY(1, true);
        BODY(2, true);
        BODY(3, true);
    }
    // tail: steps 32761..32766 (slots 0,1 reloaded for 32765/32766)
    BODY(0, true);
    BODY(1, true);
    BODY(2, false);
    BODY(3, false);
    BODY(0, false);
    BODY(1, false);
}

// ---------------- per-step CE losses + reduction ----------------
__global__ __launch_bounds__(256) void loss_kernel(const float* __restrict__ TM,
    const float* __restrict__ TE, const float* __restrict__ msAB, const float* __restrict__ msBC,
    const float* __restrict__ b_act, const float* __restrict__ b_lab, const float* __restrict__ b_dir,
    const int* __restrict__ ga, const int* __restrict__ gl, const int* __restrict__ gd,
    float* __restrict__ out)
{
    const int t = blockIdx.x * 256 + threadIdx.x;
    float loss = 0.f;
    if (t < N_STEPS) {
        const float *v1, *v0, *vb;
        if (t == 0)      { v1 = msAB; v0 = msAB + 24; vb = TE + 24; }
        else if (t == 1) { v1 = msAB; v0 = TE;        vb = TE + 48 + 24; }
        else if ((t & 1) == 0) {
            const int k = t >> 1;
            v1 = TM + (size_t)(k - 1) * 48;
            v0 = TE + (size_t)k * 48;
            vb = (k < N_EDUS - 1) ? (TE + (size_t)(k + 1) * 48 + 24) : (msBC + 24);
        } else {
            const int k = t >> 1;
            v1 = msAB;
            v0 = TM + (size_t)k * 48 + 24;
            vb = TE + (size_t)(k + 1) * 48 + 24;
        }
        float l[24];
        #pragma unroll
        for (int j = 0; j < 24; ++j) l[j] = v1[j] + v0[j] + vb[j];
        l[0] += b_act[0]; l[1] += b_act[1];
        #pragma unroll
        for (int j = 0; j < 19; ++j) l[2 + j] += b_lab[j];
        #pragma unroll
        for (int j = 0; j < 3; ++j) l[21 + j] += b_dir[j];
        const int ya = ga[t], yl = gl[t], yd = gd[t];
        {
            const float m = fmaxf(l[0], l[1]);
            const float sum = __expf(l[0] - m) + __expf(l[1] - m);
            loss += m + __logf(sum) - (ya == 0 ? l[0] : l[1]);
        }
        {
            float m = l[2];
            #pragma unroll
            for (int j = 1; j < 19; ++j) m = fmaxf(m, l[2 + j]);
            float sum = 0.f, ly = 0.f;
            #pragma unroll
            for (int j = 0; j < 19; ++j) {
                sum += __expf(l[2 + j] - m);
                if (j == yl) ly = l[2 + j];
            }
            loss += m + __logf(sum) - ly;
        }
        {
            const float m = fmaxf(fmaxf(l[21], l[22]), l[23]);
            const float sum = __expf(l[21] - m) + __expf(l[22] - m) + __expf(l[23] - m);
            const float ly = (yd == 0) ? l[21] : (yd == 1 ? l[22] : l[23]);
            loss += m + __logf(sum) - ly;
        }
    }
    #pragma unroll
    for (int off = 32; off > 0; off >>= 1) loss += __shfl_down(loss, off, 64);
    __shared__ float wsum[4];
    const int lane = threadIdx.x & 63, wv = threadIdx.x >> 6;
    if (lane == 0) wsum[wv] = loss;
    __syncthreads();
    if (threadIdx.x == 0) atomicAdd(out, wsum[0] + wsum[1] + wsum[2] + wsum[3]);
}

// ---------------- launch ----------------
extern "C" void kernel_launch(void* const* d_in, const int* in_sizes, int n_in,
                              void* d_out, int out_size, void* d_ws, size_t ws_size,
                              hipStream_t stream) {
    const float* enc_cls = (const float*)d_in[0];
    const float* W_proj  = (const float*)d_in[1];
    const float* b_proj  = (const float*)d_in[2];
    const float* miss    = (const float*)d_in[3];
    const float* W_act   = (const float*)d_in[4];
    const float* b_act   = (const float*)d_in[5];
    const float* W_lab   = (const float*)d_in[6];
    const float* b_lab   = (const float*)d_in[7];
    const float* W_dir   = (const float*)d_in[8];
    const float* b_dir   = (const float*)d_in[9];
    const float* W_tree  = (const float*)d_in[10];
    const float* b_tree  = (const float*)d_in[11];
    const int*   ga      = (const int*)d_in[12];
    const int*   gl      = (const int*)d_in[13];
    const int*   gd      = (const int*)d_in[14];
    float* out = (float*)d_out;

    float* ws   = (float*)d_ws;
    float* enc  = ws;                         // 32768*200
    float* Mar  = ws + 6553600;               // 32767*200
    float* P    = ws + 13107000;              // 32767*500 (row 0 unused)
    float* WAB  = ws + 29490500;              // 48*200
    float* WBC  = WAB + 9600;                 // 48*200
    float* msAB = WBC + 9600;                 // 48
    float* msBC = msAB + 48;                  // 48
    uint4* WA   = (uint4*)(msBC + 48);        // 8960 uint4 = 35840 dwords (A-frags)
    float* TM = P;                            // 32767*48 (overlays dead P)
    float* TE = P + 1572816;                  // 32768*48

    gemm_bt<<<dim3(512, 4, 1), 256, 0, stream>>>(enc_cls, 768, W_proj, 768, b_proj,
                                                 enc, 200, N_EDUS, 200, 768);
    gemm_bt<<<dim3(512, 8, 1), 256, 0, stream>>>(enc + 200, 200, W_tree + 100, 200, b_tree,
                                                 P + PSTRIDE, PSTRIDE, KMAX, 500, 100);
    prep_kernel<<<1, 256, 0, stream>>>(W_act, W_lab, W_dir, miss, WAB, WBC, msAB, msBC, out);
    pack_wa<<<35, 256, 0, stream>>>(W_tree, WA);
    chain_kernel<<<1, 448, 0, stream>>>(enc, WA, P, Mar);
    gemm_bt<<<dim3(512, 1, 1), 256, 0, stream>>>(Mar, 200, WAB, 200, nullptr,
                                                 TM, 48, KMAX + 1, 48, 200);
    gemm_bt<<<dim3(512, 1, 1), 256, 0, stream>>>(enc, 200, WBC, 200, nullptr,
                                                 TE, 48, N_EDUS, 48, 200);
    loss_kernel<<<dim3(256, 1, 1), 256, 0, stream>>>(TM, TE, msAB, msBC,
                                                     b_act, b_lab, b_dir, ga, gl, gd, out);
}